// Round 7
// baseline (6636.817 us; speedup 1.0000x reference)
//
#include <hip/hip_runtime.h>
#include <cstdint>
#include <cstddef>

// Problem constants (B=8, N=2048, M=256)
#define NB 8
#define NN 2048
#define MM 256

typedef unsigned long long u64;

// monotone float->uint map; canonicalize -0 to +0 so float ties == key ties
__device__ __forceinline__ unsigned mapf(float f) {
  unsigned u = __float_as_uint(f + 0.f);
  return ((int)u >= 0) ? (u ^ 0x80000000u) : ~u;
}
__device__ __forceinline__ u64 shflx_u64(u64 v, int m) {
  unsigned lo = (unsigned)__shfl_xor((int)(unsigned)v, m);
  unsigned hi = (unsigned)__shfl_xor((int)(v >> 32), m);
  return ((u64)hi << 32) | lo;
}

// ---------------------------------------------------------------------------
// Phase A: LSTM trajectory — PER-WAVE-COMPLETE steps.
//
// grid(NB,8) x 512 thr (8 waves). Block (b,q) owns m-slice [32q,32q+32);
// wave w owns m-local {4w..4w+3} END-TO-END: matvec, butterfly, activation,
// gate gather, cell update, publish — no cross-wave hop, no act LDS
// round-trip, no wave0 funnel, ONE barrier per step (round 5 had two
// barriers + LDS act exchange + single-wave publish ~700-900cy after hbuf;
// now publish issues ~400cy after BAR A from all 8 waves in parallel).
//
// Lane layout: lane = 8*r8 + c8. g = r8>>1. Lane computes TWO rows sharing
// its h reads (halves LDS instruction traffic vs round 5):
//   row_lo: (g, ml=4w+(r8&1))      row_hi: (g, ml=4w+2+(r8&1))
// Butterfly over c8 (shfl_xor 1,2,4) -> full dot in all 8 lanes of a row.
// Gate gather for this lane's own m (ml_own = r8&3): source lane
// 16*gg + 8*(r8&1) + c8 for gate gg, select lo/hi by r8&2. 16 lanes per m
// compute c,h redundantly (identical FP ops -> no drift); lanes (c8==0,
// r8<4) publish m = 4w+r8.
//
// Exchange: UNCHANGED from round 5 (2899us verified): LLC relaxed agent
// atomics, PACKED words (round 6 proved padding regresses: per-line fetch
// amplification 31.9->409MB), tagged u64, parity double-buffer, waves 0-3
// poll 64 words each into hbuf[par] with exact-tag masked reload.
// hbuf is double-buffered by parity so the single barrier is sound:
// polls at step tt+1 write hbuf[(tt+1)&1]; any wave passing BAR(tt) has
// finished reading hbuf[(tt-1)&1] (same buffer) at step tt-1.
// Progress: tag tt+1 publish requires passing poll of tag tt, which
// requires ALL blocks' waves past BAR(tt-1), hence past their tag-(tt-1)
// consumption -> parity overwrite can never outrun a consumer. Pbuf zeroed
// each launch (tag 0 never awaited).
// Matvec LDS reads use the c8-rotated slot order with pre-rotated weight
// registers (conflict-free: 8 distinct float4 spans cover all 32 banks).
// ---------------------------------------------------------------------------
__global__ __launch_bounds__(512) void lstm_kernel(
    const float* __restrict__ z_g, const float* __restrict__ dec,
    const float* __restrict__ h0, const float* __restrict__ w_ih,
    const float* __restrict__ w_hh, const float* __restrict__ b_ih,
    const float* __restrict__ b_hh, float* __restrict__ Hall,
    u64* __restrict__ Pbuf)
{
  const int b = blockIdx.x;
  const int q = blockIdx.y;
  const int tid = threadIdx.x;
  const int w = tid >> 6;          // wave 0..7 -> m-local {4w..4w+3}
  const int lane = tid & 63;
  const int r8 = lane >> 3;        // row-slot 0..7
  const int c8 = lane & 7;         // col segment 0..7
  const int g = r8 >> 1;           // gate 0..3 (i,f,g,o)
  const int ml_lo = 4 * w + (r8 & 1);
  const int grow_lo = g * 256 + 32 * q + ml_lo;
  const int grow_hi = grow_lo + 2;
  const int ml_own = r8 & 3;       // the m this lane updates

  __shared__ __align__(16) float hbuf[2][256];

  // two rows' recurrent weights, pre-rotated by c8 (conflict-free reads):
  // slot jj holds cols 32*c8 + 4*((jj+c8)&7) .. +3
  float wlo[32], whi[32];
  {
    const float* wr0 = w_hh + (size_t)grow_lo * MM + 32 * c8;
    const float* wr1 = w_hh + (size_t)grow_hi * MM + 32 * c8;
    #pragma unroll
    for (int jj = 0; jj < 8; ++jj) {
      const int sl = 4 * ((jj + c8) & 7);
      float4 v = *(const float4*)(wr0 + sl);
      wlo[4 * jj + 0] = v.x; wlo[4 * jj + 1] = v.y;
      wlo[4 * jj + 2] = v.z; wlo[4 * jj + 3] = v.w;
      float4 u = *(const float4*)(wr1 + sl);
      whi[4 * jj + 0] = u.x; whi[4 * jj + 1] = u.y;
      whi[4 * jj + 2] = u.z; whi[4 * jj + 3] = u.w;
    }
  }

  // xb for both rows: dec @ w_ih.T + b_ih + b_hh (butterfly over c8)
  float xb_lo, xb_hi;
  {
    const float* wr0 = w_ih + (size_t)grow_lo * MM + 32 * c8;
    const float* wr1 = w_ih + (size_t)grow_hi * MM + 32 * c8;
    float p0 = 0.f, p1 = 0.f;
    #pragma unroll
    for (int i = 0; i < 8; ++i) {
      float4 dv = *(const float4*)(dec + 32 * c8 + 4 * i);
      float4 a = *(const float4*)(wr0 + 4 * i);
      float4 c = *(const float4*)(wr1 + 4 * i);
      p0 += a.x * dv.x + a.y * dv.y + a.z * dv.z + a.w * dv.w;
      p1 += c.x * dv.x + c.y * dv.y + c.z * dv.z + c.w * dv.w;
    }
    p0 += __shfl_xor(p0, 1); p0 += __shfl_xor(p0, 2); p0 += __shfl_xor(p0, 4);
    p1 += __shfl_xor(p1, 1); p1 += __shfl_xor(p1, 2); p1 += __shfl_xor(p1, 4);
    xb_lo = p0 + b_ih[grow_lo] + b_hh[grow_lo];
    xb_hi = p1 + b_ih[grow_hi] + b_hh[grow_hi];
  }

  float c_my = z_g[b * MM + 32 * q + 4 * w + ml_own];
  if (tid < 256) hbuf[0][tid] = h0[tid];

  u64* Pb = Pbuf + (size_t)b * 512;
  float* Hb = Hall + (size_t)b * NN * MM;

  const bool istanh = (g == 2);
  const float kmul = istanh ? -2.f : -1.f;

  for (int tt = 0; tt < NN; ++tt) {
    // ---- poll h^(tt) into hbuf[tt&1] (waves 0-3; exact tag; masked) ----
    if (tt > 0 && w < 4) {
      const int widx = (w << 6) + lane;
      const u64* pa = Pb + ((tt & 1) << 8) + widx;
      u64 v = __hip_atomic_load(pa, __ATOMIC_RELAXED,
                                __HIP_MEMORY_SCOPE_AGENT);
      bool ok = ((unsigned)(v >> 32) == (unsigned)tt);
      while (!__all((int)ok)) {
        if (!ok) {
          v = __hip_atomic_load(pa, __ATOMIC_RELAXED,
                                __HIP_MEMORY_SCOPE_AGENT);
          ok = ((unsigned)(v >> 32) == (unsigned)tt);
        }
      }
      hbuf[tt & 1][widx] = __uint_as_float((unsigned)v);
    }
    __syncthreads();                       // the ONE barrier per step

    // ---- matvec: both rows share the 8 rotated float4 reads ----
    const float4* h4 = (const float4*)hbuf[tt & 1];
    float l0 = 0.f, l1 = 0.f, l2 = 0.f, l3 = 0.f;
    float m0 = 0.f, m1 = 0.f, m2 = 0.f, m3 = 0.f;
    #pragma unroll
    for (int jj = 0; jj < 8; ++jj) {
      float4 hv = h4[8 * c8 + ((jj + c8) & 7)];
      l0 = fmaf(hv.x, wlo[4 * jj + 0], l0);
      l1 = fmaf(hv.y, wlo[4 * jj + 1], l1);
      l2 = fmaf(hv.z, wlo[4 * jj + 2], l2);
      l3 = fmaf(hv.w, wlo[4 * jj + 3], l3);
      m0 = fmaf(hv.x, whi[4 * jj + 0], m0);
      m1 = fmaf(hv.y, whi[4 * jj + 1], m1);
      m2 = fmaf(hv.z, whi[4 * jj + 2], m2);
      m3 = fmaf(hv.w, whi[4 * jj + 3], m3);
    }
    float s_lo = (l0 + l1) + (l2 + l3);
    float s_hi = (m0 + m1) + (m2 + m3);
    s_lo += __shfl_xor(s_lo, 1); s_lo += __shfl_xor(s_lo, 2); s_lo += __shfl_xor(s_lo, 4);
    s_hi += __shfl_xor(s_hi, 1); s_hi += __shfl_xor(s_hi, 2); s_hi += __shfl_xor(s_hi, 4);
    const float g_lo = s_lo + xb_lo;
    const float g_hi = s_hi + xb_hi;

    // activations (sigmoid, or tanh for g-gate rows via kmul trick)
    float e = __expf(kmul * g_lo);
    float sg = 1.f / (1.f + e);
    const float a_lo = istanh ? 2.f * sg - 1.f : sg;
    e = __expf(kmul * g_hi);
    sg = 1.f / (1.f + e);
    const float a_hi = istanh ? 2.f * sg - 1.f : sg;

    // ---- intra-wave gate gather for this lane's m (ml_own) ----
    const int baseLane = 8 * (r8 & 1) + c8;
    const bool lohalf = (r8 & 2) == 0;     // ml_own < 2 -> a_lo
    float gi, gf, gg_, go;
    {
      float tl = __shfl(a_lo, baseLane);      float th = __shfl(a_hi, baseLane);
      gi = lohalf ? tl : th;
      tl = __shfl(a_lo, baseLane + 16);       th = __shfl(a_hi, baseLane + 16);
      gf = lohalf ? tl : th;
      tl = __shfl(a_lo, baseLane + 32);       th = __shfl(a_hi, baseLane + 32);
      gg_ = lohalf ? tl : th;
      tl = __shfl(a_lo, baseLane + 48);       th = __shfl(a_hi, baseLane + 48);
      go = lohalf ? tl : th;
    }

    // ---- cell update (16 redundant lanes per m; identical FP ops) ----
    c_my = gf * c_my + gi * gg_;
    const float e2 = __expf(-2.f * c_my);
    const float hn = go * (2.f / (1.f + e2) - 1.f);

    // ---- publish: lanes (c8==0, r8<4) own m = 4w+r8 ----
    if (c8 == 0 && r8 < 4) {
      const int mi = 32 * q + 4 * w + r8;
      const u64 pk = ((u64)(unsigned)(tt + 1) << 32) | (u64)__float_as_uint(hn);
      __hip_atomic_store(Pb + (((tt + 1) & 1) << 8) + mi, pk,
                         __ATOMIC_RELAXED, __HIP_MEMORY_SCOPE_AGENT);
      Hb[(size_t)tt * MM + mi] = hn;     // trajectory for the Q gemm
    }
  }
}

// ---------------------------------------------------------------------------
// C = A @ B^T (+ col bias). 128x128 tile, 256 threads, 8x8 micro-tile.
// ---------------------------------------------------------------------------
__global__ __launch_bounds__(256) void gemm128(
    const float* __restrict__ A, const float* __restrict__ B,
    float* __restrict__ C, const float* __restrict__ bias,
    int K, int Ncol, long sA, long sB, long sC)
{
  __shared__ __align__(16) float As[32][132];
  __shared__ __align__(16) float Bs[32][132];
  const int tid = threadIdx.x;
  const int tx = tid & 15;
  const int ty = tid >> 4;
  const int row0 = blockIdx.y * 128;
  const int col0 = blockIdx.x * 128;
  const float* Ab = A + (size_t)blockIdx.z * (size_t)sA;
  const float* Bb = B + (size_t)blockIdx.z * (size_t)sB;
  float* Cb = C + (size_t)blockIdx.z * (size_t)sC;

  float acc[8][8];
  #pragma unroll
  for (int i = 0; i < 8; ++i)
    #pragma unroll
    for (int jj = 0; jj < 8; ++jj) acc[i][jj] = 0.f;

  for (int k0 = 0; k0 < K; k0 += 32) {
    #pragma unroll
    for (int it = 0; it < 4; ++it) {
      const int idx = tid + it * 256;
      const int r = idx >> 3;
      const int c4 = (idx & 7) << 2;
      float4 va = *(const float4*)(Ab + (size_t)(row0 + r) * K + k0 + c4);
      float4 vb = *(const float4*)(Bb + (size_t)(col0 + r) * K + k0 + c4);
      As[c4 + 0][r] = va.x; As[c4 + 1][r] = va.y;
      As[c4 + 2][r] = va.z; As[c4 + 3][r] = va.w;
      Bs[c4 + 0][r] = vb.x; Bs[c4 + 1][r] = vb.y;
      Bs[c4 + 2][r] = vb.z; Bs[c4 + 3][r] = vb.w;
    }
    __syncthreads();
    #pragma unroll
    for (int kk = 0; kk < 32; ++kk) {
      float4 a0 = *(const float4*)&As[kk][ty * 4];
      float4 a1 = *(const float4*)&As[kk][64 + ty * 4];
      float4 b0 = *(const float4*)&Bs[kk][tx * 4];
      float4 b1 = *(const float4*)&Bs[kk][64 + tx * 4];
      const float av[8] = {a0.x, a0.y, a0.z, a0.w, a1.x, a1.y, a1.z, a1.w};
      const float bv[8] = {b0.x, b0.y, b0.z, b0.w, b1.x, b1.y, b1.z, b1.w};
      #pragma unroll
      for (int i = 0; i < 8; ++i)
        #pragma unroll
        for (int jj = 0; jj < 8; ++jj)
          acc[i][jj] = fmaf(av[i], bv[jj], acc[i][jj]);
    }
    __syncthreads();
  }

  #pragma unroll
  for (int i = 0; i < 8; ++i) {
    const int r = row0 + ((i < 4) ? (ty * 4 + i) : (64 + ty * 4 + i - 4));
    float* cp = Cb + (size_t)r * Ncol + col0;
    float4 o0, o1;
    float* o0p = &o0.x; float* o1p = &o1.x;
    #pragma unroll
    for (int jj = 0; jj < 4; ++jj) {
      float v0 = acc[i][jj], v1 = acc[i][jj + 4];
      if (bias) {
        v0 += bias[col0 + tx * 4 + jj];
        v1 += bias[col0 + 64 + tx * 4 + jj];
      }
      o0p[jj] = v0; o1p[jj] = v1;
    }
    *(float4*)(cp + tx * 4) = o0;
    *(float4*)(cp + 64 + tx * 4) = o1;
  }
}

// ---------------------------------------------------------------------------
// Phase D: exact greedy masked argmax chain, one block (512 thr) per batch.
// ---------------------------------------------------------------------------
__global__ __launch_bounds__(512) void select_block(
    const float* __restrict__ S, int* __restrict__ sel)
{
  const int b = blockIdx.x;
  const int tid = threadIdx.x;
  const int w = tid >> 6;          // 0..7
  const int lane = tid & 63;
  const float* Sb = S + (size_t)b * NN * NN + 4 * tid;
  int* selb = sel + b * NN;

  __shared__ u64 partial[2][8];

  for (int i = tid; i < NN; i += 512) selb[i] = 0x7fffffff;
  __syncthreads();

  unsigned mybits = 0;                 // used flags for my 4 columns
  const unsigned base = 2047u - 4u * (unsigned)tid;

  auto stepf = [&](float4 v, int t) {
    u64 k0 = (mybits & 1u) ? 0 : (((u64)mapf(v.x) << 32) | (base - 0u));
    u64 k1 = (mybits & 2u) ? 0 : (((u64)mapf(v.y) << 32) | (base - 1u));
    u64 k2 = (mybits & 4u) ? 0 : (((u64)mapf(v.z) << 32) | (base - 2u));
    u64 k3 = (mybits & 8u) ? 0 : (((u64)mapf(v.w) << 32) | (base - 3u));
    u64 k = k0 > k1 ? k0 : k1;
    if (k2 > k) k = k2;
    if (k3 > k) k = k3;
    #pragma unroll
    for (int off = 1; off < 64; off <<= 1) {
      u64 o = shflx_u64(k, off);
      if (o > k) k = o;
    }
    if (lane == 0) partial[t & 1][w] = k;
    __syncthreads();
    u64 pk = partial[t & 1][lane & 7];
    #pragma unroll
    for (int off = 1; off < 8; off <<= 1) {
      u64 o = shflx_u64(pk, off);
      if (o > pk) pk = o;
    }
    const int idx = 2047 - (int)(pk & 0x7ff);
    if ((idx >> 2) == tid) mybits |= 1u << (idx & 3);
    if (tid == 0) selb[idx] = t;
  };

  float4 r0 = *(const float4*)(Sb + (size_t)0 * NN);
  float4 r1 = *(const float4*)(Sb + (size_t)1 * NN);
  float4 r2 = *(const float4*)(Sb + (size_t)2 * NN);
  float4 r3 = *(const float4*)(Sb + (size_t)3 * NN);
  for (int t = 0; t < NN; t += 4) {
    const size_t p4 = (size_t)((t + 4 < NN) ? t + 4 : NN - 1) * NN;
    const size_t p5 = (size_t)((t + 5 < NN) ? t + 5 : NN - 1) * NN;
    const size_t p6 = (size_t)((t + 6 < NN) ? t + 6 : NN - 1) * NN;
    const size_t p7 = (size_t)((t + 7 < NN) ? t + 7 : NN - 1) * NN;
    stepf(r0, t);     r0 = *(const float4*)(Sb + p4);
    stepf(r1, t + 1); r1 = *(const float4*)(Sb + p5);
    stepf(r2, t + 2); r2 = *(const float4*)(Sb + p6);
    stepf(r3, t + 3); r3 = *(const float4*)(Sb + p7);
  }
}

// ---------------------------------------------------------------------------
// Phase E: in-place masked softmax per row. Row t masks n iff sel[n] < t.
// ---------------------------------------------------------------------------
__global__ __launch_bounds__(256) void softmax_kernel(
    float* __restrict__ out, const int* __restrict__ sel)
{
  const int t = blockIdx.x;
  const int b = blockIdx.y;
  const int tid = threadIdx.x;
  float* row = out + ((size_t)b * NN + t) * NN;
  const int* selb = sel + b * NN;
  __shared__ float red[8];

  float v[8];
  int sl[8];
  #pragma unroll
  for (int u = 0; u < 2; ++u) {
    float4 f = *(const float4*)(row + u * 1024 + tid * 4);
    int4 s4 = *(const int4*)(selb + u * 1024 + tid * 4);
    v[u * 4 + 0] = f.x; v[u * 4 + 1] = f.y; v[u * 4 + 2] = f.z; v[u * 4 + 3] = f.w;
    sl[u * 4 + 0] = s4.x; sl[u * 4 + 1] = s4.y; sl[u * 4 + 2] = s4.z; sl[u * 4 + 3] = s4.w;
  }

  float mx = -3.0e38f;
  #pragma unroll
  for (int e = 0; e < 8; ++e)
    if (sl[e] >= t) mx = fmaxf(mx, v[e]);
  #pragma unroll
  for (int off = 1; off < 64; off <<= 1) mx = fmaxf(mx, __shfl_xor(mx, off));
  if ((tid & 63) == 0) red[tid >> 6] = mx;
  __syncthreads();
  mx = fmaxf(fmaxf(red[0], red[1]), fmaxf(red[2], red[3]));

  float e8[8];
  float sum = 0.f;
  #pragma unroll
  for (int e = 0; e < 8; ++e) {
    float ex = (sl[e] >= t) ? __expf(v[e] - mx) : 0.f;
    e8[e] = ex;
    sum += ex;
  }
  #pragma unroll
  for (int off = 1; off < 64; off <<= 1) sum += __shfl_xor(sum, off);
  if ((tid & 63) == 0) red[4 + (tid >> 6)] = sum;
  __syncthreads();
  sum = red[4] + red[5] + red[6] + red[7];
  const float inv = 1.f / sum;

  #pragma unroll
  for (int u = 0; u < 2; ++u) {
    float4 o;
    o.x = e8[u * 4 + 0] * inv; o.y = e8[u * 4 + 1] * inv;
    o.z = e8[u * 4 + 2] * inv; o.w = e8[u * 4 + 3] * inv;
    *(float4*)(row + u * 1024 + tid * 4) = o;
  }
}

// ---------------------------------------------------------------------------
// ws layout (floats): keys[4194304] | Q[4194304] | Pbuf(u64 4096 = 32KB,
//                     PACKED) | sel[16384]   ~ 33.7 MB
// Hall (h trajectory, [B][NN][256] f32 = 16.8MB) borrows d_out (134MB),
// consumed by the Q gemm before gemm2 overwrites it.
// ---------------------------------------------------------------------------
extern "C" void kernel_launch(void* const* d_in, const int* in_sizes, int n_in,
                              void* d_out, int out_size, void* d_ws, size_t ws_size,
                              hipStream_t stream)
{
  (void)in_sizes; (void)n_in; (void)out_size; (void)ws_size;
  const float* emb  = (const float*)d_in[0];
  const float* z_g  = (const float*)d_in[1];
  const float* dec  = (const float*)d_in[2];
  const float* h0   = (const float*)d_in[3];
  const float* w_ih = (const float*)d_in[4];
  const float* w_hh = (const float*)d_in[5];
  const float* b_ih = (const float*)d_in[6];
  const float* b_hh = (const float*)d_in[7];
  const float* Wq   = (const float*)d_in[8];
  const float* bq   = (const float*)d_in[9];
  const float* Wk   = (const float*)d_in[10];
  const float* bk   = (const float*)d_in[11];
  float* out = (float*)d_out;
  float* ws  = (float*)d_ws;

  float* keys  = ws;
  float* Q     = ws + 4194304;
  u64*   Pbuf  = (u64*)(ws + 8388608);    // 4096 u64 = 32 KB (packed)
  int*   sel   = (int*)(ws + 8396800);
  float* Hall  = out;                     // borrowed until the Q gemm

  // zero exchange tags (tag 0 never awaited; awaited tags >= 1)
  hipMemsetAsync(Pbuf, 0, 4096 * sizeof(u64), stream);

  lstm_kernel<<<dim3(NB, 8), 512, 0, stream>>>(
      z_g, dec, h0, w_ih, w_hh, b_ih, b_hh, Hall, Pbuf);

  // Q = Hall @ Wq.T + bq  ([16384,256] x [256,256]^T)
  gemm128<<<dim3(MM / 128, (NB * NN) / 128, 1), 256, 0, stream>>>(
      Hall, Wq, Q, bq, MM, MM, 0, 0, 0);

  // keys = emb @ Wk.T + bk
  gemm128<<<dim3(MM / 128, (NB * NN) / 128, 1), 256, 0, stream>>>(
      emb, Wk, keys, bk, MM, MM, 0, 0, 0);

  // S[b] = Q[b] @ keys[b].T -> d_out (overwrites Hall, already consumed)
  gemm128<<<dim3(NN / 128, NN / 128, NB), 256, 0, stream>>>(
      Q, keys, out, nullptr, MM, NN,
      (long)NN * MM, (long)NN * MM, (long)NN * NN);

  select_block<<<NB, 512, 0, stream>>>(out, sel);

  softmax_kernel<<<dim3(NN, NB), 256, 0, stream>>>(out, sel);
}